// Round 5
// baseline (66.400 us; speedup 1.0000x reference)
//
#include <hip/hip_runtime.h>
#include <hip/hip_bf16.h>

// GQA paged-prefill attention, MI355X gfx950.
// Causal mask j<=i over concat(past,new) => only first Q_LEN (=1024) gathered
// past tokens are live. Flash-attention over tokens 0..1023 of paged cache.
//
// R5: KV-split (flash-decoding). qt>=8 blocks split into half0 (kv tiles 0..7)
// and half1 (tiles 8..qt); partials (unnorm acc, m, l) combined by a second
// kernel. Makespan drops 16 -> ~9 tile-iterations. half0 acc parked in d_out,
// half1 acc in d_ws (~8.1 MB). Everything else = R4 structure.

#define NUM_HEADS 32
#define HEAD_DIM 128
#define Q_STRIDE 4096
#define SCALE 0.08838834764831845f
#define RESCALE_THR 8.0f

typedef short short8 __attribute__((ext_vector_type(8)));
typedef float f32x4 __attribute__((ext_vector_type(4)));
typedef unsigned short ushort_t;
typedef unsigned int uint_t;

// ws float layout: acc1[256][64][128] | ml0[256][64][2] | ml1[256][64][2]
#define WS_ACC1 0
#define WS_ML0  (256 * 64 * 128)
#define WS_ML1  (WS_ML0 + 256 * 64 * 2)

__device__ __forceinline__ ushort_t f2bf(float f) {
    return __builtin_bit_cast(ushort_t, __float2bfloat16(f));
}
__device__ __forceinline__ uint_t pk2(float a, float b) {
    return (uint_t)f2bf(a) | ((uint_t)f2bf(b) << 16);
}

// ---- staging macros: static indices only, no address escapes ----
#define KLOAD(JB)                                                            \
    _Pragma("unroll")                                                        \
    for (int k = 0; k < 4; ++k) {                                            \
        const int page = sPages[(JB) * 4 + k];                               \
        const float* src = kvc + (size_t)page * 32768                       \
                         + (size_t)hkv * 2048 + kt0 * 128 + kh16 * 8;       \
        kr[2 * k]     = *(const float4*)src;                                 \
        kr[2 * k + 1] = *(const float4*)(src + 4);                           \
    }

#define KSTORE(DST)                                                          \
    _Pragma("unroll")                                                        \
    for (int k = 0; k < 4; ++k) {                                            \
        uint4 p;                                                             \
        p.x = pk2(kr[2*k].x,   kr[2*k].y);                                   \
        p.y = pk2(kr[2*k].z,   kr[2*k].w);                                   \
        p.z = pk2(kr[2*k+1].x, kr[2*k+1].y);                                 \
        p.w = pk2(kr[2*k+1].z, kr[2*k+1].w);                                 \
        const uint_t byte = (uint_t)((kt0 + k * 16) * 256)                   \
                          + (((uint_t)(kh16 * 16)) ^ kswz);                  \
        *(uint4*)((DST) + byte) = p;                                         \
    }

#define VLOAD(JB)                                                            \
    {                                                                        \
        const int page = sPages[(JB) * 4 + (vtp >> 3)];                      \
        const float* src = kvc + (size_t)page * 32768 + 16384               \
                         + (size_t)hkv * 2048 + ((2 * vtp) & 15) * 128      \
                         + vc * 16;                                          \
        _Pragma("unroll")                                                    \
        for (int i = 0; i < 4; ++i) {                                        \
            vr[i]     = ((const float4*)src)[i];                             \
            vr[4 + i] = ((const float4*)(src + 128))[i];                     \
        }                                                                    \
    }

#define VSTORE(DST)                                                          \
    _Pragma("unroll")                                                        \
    for (int dv = 0; dv < 16; ++dv) {                                        \
        const int d = vc * 16 + dv;                                          \
        const uint_t byte = ((uint_t)(d * 128 + 4 * vtp))                    \
                          ^ ((uint_t)((d & 7) << 4));                        \
        *(uint_t*)((DST) + byte) = pk2(vr[dv >> 2][dv & 3],                  \
                                       vr[4 + (dv >> 2)][dv & 3]);           \
    }

__launch_bounds__(256)
__global__ void attn_paged_prefill(const float* __restrict__ q,
                                   const float* __restrict__ kvc,
                                   const int* __restrict__ bt,
                                   float* __restrict__ out,
                                   float* __restrict__ ws)
{
    __shared__ __align__(16) char sK[2][64 * 256];    // 2 x 16 KB
    __shared__ __align__(16) char sV[2][128 * 128];   // 2 x 16 KB
    __shared__ __align__(16) char sP[4][2048];        // 8 KB
    __shared__ int sPages[64];

    const int bid = blockIdx.x;
    const int h   = bid & 31;
    // mode 0 = direct (qt<8), 1 = half0 (tiles 0..7), 2 = half1 (tiles 8..qt)
    int qt, jb0, jb1, mode;
    if (bid < 256)      { qt = 15 - (bid >> 5);         jb0 = 0; jb1 = 7;  mode = 1; }
    else if (bid < 512) { qt = 15 - ((bid - 256) >> 5); jb0 = 8; jb1 = qt; mode = 2; }
    else                { qt = 7  - ((bid - 512) >> 5); jb0 = 0; jb1 = qt; mode = 0; }
    const int hkv = h >> 2;
    const int tid  = threadIdx.x;
    const int w    = tid >> 6;
    const int lane = tid & 63;
    const int l15  = lane & 15;
    const int lhi  = lane >> 4;

    if (tid < 64) sPages[tid] = bt[tid];

    // K gather geometry: thread -> (token kt0 + k*16, 16B chunk kh16)
    const int kh16 = tid & 15;
    const int kt0  = tid >> 4;
    const uint_t kswz = (uint_t)((kt0 & 7) << 4);
    // V gather geometry: thread -> token pair (2*vtp, 2*vtp+1), dim chunk vc
    const int vtp = lane & 31;
    const int vc  = w * 2 + (lane >> 5);

    // ---- Q fragments (SCALE folded): wave w owns rows qt*64 + w*16 + l15
    short8 qf[4];
    {
        const int qrow = qt * 64 + w * 16 + l15;
        const float* qp = q + (size_t)qrow * Q_STRIDE + h * HEAD_DIM;
#pragma unroll
        for (int s = 0; s < 4; ++s) {
            const int d0 = s * 32 + lhi * 8;
            float4 a = *(const float4*)(qp + d0);
            float4 b = *(const float4*)(qp + d0 + 4);
            short8 v;
            v[0] = (short)f2bf(a.x * SCALE); v[1] = (short)f2bf(a.y * SCALE);
            v[2] = (short)f2bf(a.z * SCALE); v[3] = (short)f2bf(a.w * SCALE);
            v[4] = (short)f2bf(b.x * SCALE); v[5] = (short)f2bf(b.y * SCALE);
            v[6] = (short)f2bf(b.z * SCALE); v[7] = (short)f2bf(b.w * SCALE);
            qf[s] = v;
        }
    }

    f32x4 acc[8];
#pragma unroll
    for (int n2 = 0; n2 < 8; ++n2) acc[n2] = (f32x4){0.f, 0.f, 0.f, 0.f};
    float m_run[4]  = {-1e30f, -1e30f, -1e30f, -1e30f};
    float l_part[4] = {0.f, 0.f, 0.f, 0.f};

    __syncthreads();   // sPages visible

    float4 kr[8], vr[8];
    // prologue: first tile -> buf 0
    KLOAD(jb0)
    VLOAD(jb0)
    KSTORE(sK[0])
    VSTORE(sV[0])
    __syncthreads();

    for (int jb = jb0; jb <= jb1; ++jb) {
        const int cur = (jb - jb0) & 1;
        char* kbuf = sK[cur];
        char* vbuf = sV[cur];
        const bool pf = (jb < jb1);
        if (pf) {            // issue next tile's loads; fly under compute
            KLOAD(jb + 1)
            VLOAD(jb + 1)
        }

        // ---- S = Q K^T
        f32x4 sacc[4];
#pragma unroll
        for (int n = 0; n < 4; ++n) sacc[n] = (f32x4){0.f, 0.f, 0.f, 0.f};
#pragma unroll
        for (int s = 0; s < 4; ++s) {
#pragma unroll
            for (int n = 0; n < 4; ++n) {
                const int tok = n * 16 + l15;
                const uint_t byte = (uint_t)(tok * 256)
                    + (((uint_t)((s * 32 + lhi * 8) * 2)) ^ ((uint_t)((tok & 7) << 4)));
                short8 kb = *(const short8*)(kbuf + byte);
                sacc[n] = __builtin_amdgcn_mfma_f32_16x16x32_bf16(qf[s], kb, sacc[n], 0, 0, 0);
            }
        }

        // ---- softmax with deferred max
        const bool diag = (jb == qt);
        float pv[4][4];
#pragma unroll
        for (int n = 0; n < 4; ++n)
#pragma unroll
            for (int j = 0; j < 4; ++j) {
                float x = sacc[n][j];
                if (diag) {
                    const int tok = jb * 64 + n * 16 + l15;
                    const int qg  = qt * 64 + w * 16 + lhi * 4 + j;
                    if (tok > qg) x = -1e30f;
                }
                pv[n][j] = x;
            }
#pragma unroll
        for (int j = 0; j < 4; ++j) {
            float lmax = fmaxf(fmaxf(pv[0][j], pv[1][j]), fmaxf(pv[2][j], pv[3][j]));
            if (__any(lmax > m_run[j] + RESCALE_THR)) {
                float mt = lmax;
#pragma unroll
                for (int off = 1; off < 16; off <<= 1)
                    mt = fmaxf(mt, __shfl_xor(mt, off));
                const float mn = fmaxf(m_run[j], mt);
                const float alpha = __expf(m_run[j] - mn);
                m_run[j] = mn;
                l_part[j] *= alpha;
#pragma unroll
                for (int n2 = 0; n2 < 8; ++n2) acc[n2][j] *= alpha;
            }
            float ls = 0.f;
#pragma unroll
            for (int n = 0; n < 4; ++n) {
                float p = __expf(pv[n][j] - m_run[j]);
                pv[n][j] = p;
                ls += p;
            }
            l_part[j] += ls;
        }

        // ---- P -> per-wave LDS (A-fragment relayout)
        char* pb = sP[w];
#pragma unroll
        for (int n = 0; n < 4; ++n)
#pragma unroll
            for (int j = 0; j < 4; ++j) {
                const int r = lhi * 4 + j;
                const uint_t byte = (uint_t)(r * 128)
                    + (((uint_t)((n * 16 + l15) * 2)) ^ ((uint_t)((r & 7) << 4)));
                *(ushort_t*)(pb + byte) = f2bf(pv[n][j]);
            }

        // ---- O += P V
#pragma unroll
        for (int s2 = 0; s2 < 2; ++s2) {
            const uint_t pbyte = (uint_t)(l15 * 128)
                + (((uint_t)((s2 * 32 + lhi * 8) * 2)) ^ ((uint_t)((l15 & 7) << 4)));
            short8 pa = *(const short8*)(pb + pbyte);
#pragma unroll
            for (int n2 = 0; n2 < 8; ++n2) {
                const int dim = n2 * 16 + l15;
                const uint_t vbyte = (uint_t)(dim * 128)
                    + (((uint_t)((s2 * 32 + lhi * 8) * 2)) ^ ((uint_t)((dim & 7) << 4)));
                short8 vbf = *(const short8*)(vbuf + vbyte);
                acc[n2] = __builtin_amdgcn_mfma_f32_16x16x32_bf16(pa, vbf, acc[n2], 0, 0, 0);
            }
        }

        if (pf) {
            char* kn = sK[cur ^ 1];
            char* vn = sV[cur ^ 1];
            KSTORE(kn)
            VSTORE(vn)
            __syncthreads();
        }
    }

    // ---- epilogue
    const int pidx = (15 - qt) * 32 + h;   // valid for mode 1/2
#pragma unroll
    for (int j = 0; j < 4; ++j) {
        float lsum = l_part[j];
#pragma unroll
        for (int off = 1; off < 16; off <<= 1)
            lsum += __shfl_xor(lsum, off);
        const int row = w * 16 + lhi * 4 + j;        // row within 64-row tile
        const int qg  = qt * 64 + row;
        if (mode == 0) {
            const float inv = 1.0f / lsum;
            float* dst = out + (size_t)qg * Q_STRIDE + h * HEAD_DIM;
#pragma unroll
            for (int n2 = 0; n2 < 8; ++n2)
                dst[n2 * 16 + l15] = acc[n2][j] * inv;
        } else if (mode == 1) {
            // unnormalized acc parked in out; (m,l) to ws ml0
            float* dst = out + (size_t)qg * Q_STRIDE + h * HEAD_DIM;
#pragma unroll
            for (int n2 = 0; n2 < 8; ++n2)
                dst[n2 * 16 + l15] = acc[n2][j];
            if (l15 == 0) {
                float* ml = ws + WS_ML0 + (size_t)(pidx * 64 + row) * 2;
                ml[0] = m_run[j];
                ml[1] = lsum;
            }
        } else {
            float* dst = ws + WS_ACC1 + (size_t)(pidx * 64 + row) * 128;
#pragma unroll
            for (int n2 = 0; n2 < 8; ++n2)
                dst[n2 * 16 + l15] = acc[n2][j];
            if (l15 == 0) {
                float* ml = ws + WS_ML1 + (size_t)(pidx * 64 + row) * 2;
                ml[0] = m_run[j];
                ml[1] = lsum;
            }
        }
    }
}

__launch_bounds__(256)
__global__ void attn_combine(float* __restrict__ out, const float* __restrict__ ws)
{
    const int pidx = blockIdx.x;          // 0..255
    const int qt = 15 - (pidx >> 5);
    const int h  = pidx & 31;
    const int t  = threadIdx.x;
    const int dl = (t & 31) * 4;          // dim offset (float4)
    const int r0 = t >> 5;                // row 0..7, step 8

#pragma unroll
    for (int p = 0; p < 8; ++p) {
        const int r = r0 + p * 8;
        const float* ml0 = ws + WS_ML0 + (size_t)(pidx * 64 + r) * 2;
        const float* ml1 = ws + WS_ML1 + (size_t)(pidx * 64 + r) * 2;
        const float m1 = ml0[0], l1 = ml0[1];
        const float m2 = ml1[0], l2 = ml1[1];
        const float m  = fmaxf(m1, m2);
        const float a1 = __expf(m1 - m), a2 = __expf(m2 - m);
        const float inv = 1.0f / (l1 * a1 + l2 * a2);
        float* o = out + (size_t)(qt * 64 + r) * Q_STRIDE + h * HEAD_DIM + dl;
        const float* p2 = ws + WS_ACC1 + (size_t)(pidx * 64 + r) * 128 + dl;
        float4 x = *(const float4*)o;
        float4 y = *(const float4*)p2;
        x.x = (x.x * a1 + y.x * a2) * inv;
        x.y = (x.y * a1 + y.y * a2) * inv;
        x.z = (x.z * a1 + y.z * a2) * inv;
        x.w = (x.w * a1 + y.w * a2) * inv;
        *(float4*)o = x;
    }
}

extern "C" void kernel_launch(void* const* d_in, const int* in_sizes, int n_in,
                              void* d_out, int out_size, void* d_ws, size_t ws_size,
                              hipStream_t stream) {
    const float* q   = (const float*)d_in[0];
    // d_in[1] (k) and d_in[2] (v) are dead under the reference's causal mask.
    const float* kvc = (const float*)d_in[3];
    const int*   bt  = (const int*)d_in[4];
    float* out = (float*)d_out;
    float* ws  = (float*)d_ws;
    attn_paged_prefill<<<dim3(768), dim3(256), 0, stream>>>(q, kvc, bt, out, ws);
    attn_combine<<<dim3(256), dim3(256), 0, stream>>>(out, ws);
}

// Round 6
// 45.796 us; speedup vs baseline: 1.4499x; 1.4499x over previous
//
#include <hip/hip_runtime.h>
#include <hip/hip_bf16.h>

// GQA paged-prefill attention, MI355X gfx950.
// Causal mask j<=i over concat(past,new) => only first Q_LEN (=1024) gathered
// past tokens are live. Flash-attention over tokens 0..1023 of paged cache.
//
// R6: two-kernel design.
//  prep_kv: gather+convert KV to bf16 ONCE into d_ws, dense, with the LDS
//           XOR-swizzle baked into the global layout (K row-major tiles,
//           V transposed tiles).
//  attn_main: stages K/V tiles via global_load_lds width=16 (pure DMA, no
//           VGPR roundtrip, no converts), double-buffered, 1 barrier/tile.

#define NUM_HEADS 32
#define HEAD_DIM 128
#define Q_STRIDE 4096
#define SCALE 0.08838834764831845f
#define RESCALE_THR 8.0f
#define KSW_TILE 16384                 // bytes per (hkv, jb) tile
#define VSW_OFF (2 * 1024 * 1024)      // Vt tiles start 2MB into ws

typedef short short8 __attribute__((ext_vector_type(8)));
typedef float f32x4 __attribute__((ext_vector_type(4)));
typedef unsigned short ushort_t;
typedef unsigned int uint_t;

__device__ __forceinline__ ushort_t f2bf(float f) {
    return __builtin_bit_cast(ushort_t, __float2bfloat16(f));
}
__device__ __forceinline__ uint_t pk2(float a, float b) {
    return (uint_t)f2bf(a) | ((uint_t)f2bf(b) << 16);
}

// ---------------- prep: paged fp32 -> dense swizzled bf16 ----------------
__launch_bounds__(256)
__global__ void prep_kv(const float* __restrict__ kvc,
                        const int* __restrict__ bt,
                        char* __restrict__ wsb)
{
    __shared__ float sVt[64 * 128];
    const int blk = blockIdx.x;        // 128 blocks = hkv(8) x jb(16)
    const int hkv = blk >> 4;
    const int jb  = blk & 15;
    const int tid = threadIdx.x;
    char* kout = wsb + (size_t)(hkv * 16 + jb) * KSW_TILE;
    char* vout = wsb + VSW_OFF + (size_t)(hkv * 16 + jb) * KSW_TILE;

    // K: [t 64][d 128] bf16, 16B chunk c at byte t*256 + ((c*16)^((t&7)<<4))
#pragma unroll
    for (int i = 0; i < 4; ++i) {
        const int u = tid + i * 256;   // t(64) x c(16)
        const int t = u >> 4, c = u & 15;
        const int gtok = jb * 64 + t;
        const int page = bt[gtok >> 4];
        const float* src = kvc + (size_t)page * 32768 + (size_t)hkv * 2048
                         + (gtok & 15) * 128 + c * 8;
        float4 a = *(const float4*)src;
        float4 b = *(const float4*)(src + 4);
        uint4 p;
        p.x = pk2(a.x, a.y); p.y = pk2(a.z, a.w);
        p.z = pk2(b.x, b.y); p.w = pk2(b.z, b.w);
        *(uint4*)(kout + t * 256 + ((c * 16) ^ ((t & 7) << 4))) = p;
    }
    // V: coalesced fp32 read -> LDS
#pragma unroll
    for (int i = 0; i < 8; ++i) {
        const int u = tid + i * 256;   // t(64) x c4(32)
        const int t = u >> 5, c4 = u & 31;
        const int gtok = jb * 64 + t;
        const int page = bt[gtok >> 4];
        const float* src = kvc + (size_t)page * 32768 + 16384
                         + (size_t)hkv * 2048 + (gtok & 15) * 128 + c4 * 4;
        *(float4*)(sVt + t * 128 + c4 * 4) = *(const float4*)src;
    }
    __syncthreads();
    // Vt: [d 128][t 64] bf16, 16B chunk ch at byte (d*128+16*ch)^((d&7)<<4)
#pragma unroll
    for (int i = 0; i < 4; ++i) {
        const int u = tid + i * 256;   // d(128) x ch(8)
        const int d = u >> 3, ch = u & 7;
        float v[8];
#pragma unroll
        for (int k = 0; k < 8; ++k) v[k] = sVt[(8 * ch + k) * 128 + d];
        uint4 p;
        p.x = pk2(v[0], v[1]); p.y = pk2(v[2], v[3]);
        p.z = pk2(v[4], v[5]); p.w = pk2(v[6], v[7]);
        *(uint4*)(vout + ((d * 128 + 16 * ch) ^ ((d & 7) << 4))) = p;
    }
}

// ---------------- main attention ----------------
#define GLL16(G, L) __builtin_amdgcn_global_load_lds(                         \
    (const uint_t __attribute__((address_space(1)))*)(G),                     \
    (uint_t __attribute__((address_space(3)))*)(L), 16, 0, 0)

// Stage tile JB: linear DMA; swizzle already baked into the global layout.
// LDS dest is wave-uniform base (+ implicit lane*16); global src is per-lane.
#define STAGE(JB, KB, VB) {                                                   \
    const char* ks = kvbf + (size_t)(hkv * 16 + (JB)) * KSW_TILE              \
                   + w * 4096 + lane * 16;                                    \
    const char* vs = ks + VSW_OFF;                                            \
    _Pragma("unroll")                                                         \
    for (int i = 0; i < 4; ++i) {                                             \
        GLL16(ks + i * 1024, (KB) + w * 4096 + i * 1024);                     \
        GLL16(vs + i * 1024, (VB) + w * 4096 + i * 1024);                     \
    }                                                                         \
}

__launch_bounds__(256)
__global__ void attn_main(const float* __restrict__ q,
                          const char* __restrict__ kvbf,
                          float* __restrict__ out)
{
    __shared__ __align__(16) char sK[2][16384];
    __shared__ __align__(16) char sV[2][16384];
    __shared__ __align__(16) char sP[4][2048];

    const int bid = blockIdx.x;
    const int h   = bid & 31;
    const int qt  = 15 - (bid >> 5);   // long blocks first
    const int hkv = h >> 2;
    const int tid  = threadIdx.x;
    const int w    = tid >> 6;
    const int lane = tid & 63;
    const int l15  = lane & 15;
    const int lhi  = lane >> 4;

    // ---- Q fragments (SCALE folded): wave w owns rows qt*64 + w*16 + l15
    short8 qf[4];
    {
        const int qrow = qt * 64 + w * 16 + l15;
        const float* qp = q + (size_t)qrow * Q_STRIDE + h * HEAD_DIM;
#pragma unroll
        for (int s = 0; s < 4; ++s) {
            const int d0 = s * 32 + lhi * 8;
            float4 a = *(const float4*)(qp + d0);
            float4 b = *(const float4*)(qp + d0 + 4);
            short8 v;
            v[0] = (short)f2bf(a.x * SCALE); v[1] = (short)f2bf(a.y * SCALE);
            v[2] = (short)f2bf(a.z * SCALE); v[3] = (short)f2bf(a.w * SCALE);
            v[4] = (short)f2bf(b.x * SCALE); v[5] = (short)f2bf(b.y * SCALE);
            v[6] = (short)f2bf(b.z * SCALE); v[7] = (short)f2bf(b.w * SCALE);
            qf[s] = v;
        }
    }

    f32x4 acc[8];
#pragma unroll
    for (int n2 = 0; n2 < 8; ++n2) acc[n2] = (f32x4){0.f, 0.f, 0.f, 0.f};
    float m_run[4]  = {-1e30f, -1e30f, -1e30f, -1e30f};
    float l_part[4] = {0.f, 0.f, 0.f, 0.f};

    // prologue: tile 0 -> buf 0 (syncthreads drains vmcnt incl. gll)
    STAGE(0, sK[0], sV[0])
    __syncthreads();

    for (int jb = 0; jb <= qt; ++jb) {
        const int cur = jb & 1;
        char* kbuf = sK[cur];
        char* vbuf = sV[cur];
        const bool pf = (jb < qt);
        if (pf) {           // DMA next tile into other buffer; flies under compute
            STAGE(jb + 1, sK[cur ^ 1], sV[cur ^ 1])
        }

        // ---- S = Q K^T
        f32x4 sacc[4];
#pragma unroll
        for (int n = 0; n < 4; ++n) sacc[n] = (f32x4){0.f, 0.f, 0.f, 0.f};
#pragma unroll
        for (int s = 0; s < 4; ++s) {
#pragma unroll
            for (int n = 0; n < 4; ++n) {
                const int tok = n * 16 + l15;
                const uint_t byte = (uint_t)(tok * 256)
                    + (((uint_t)((s * 32 + lhi * 8) * 2)) ^ ((uint_t)((tok & 7) << 4)));
                short8 kb = *(const short8*)(kbuf + byte);
                sacc[n] = __builtin_amdgcn_mfma_f32_16x16x32_bf16(qf[s], kb, sacc[n], 0, 0, 0);
            }
        }

        // ---- softmax with deferred max
        const bool diag = (jb == qt);
        float pv[4][4];
#pragma unroll
        for (int n = 0; n < 4; ++n)
#pragma unroll
            for (int j = 0; j < 4; ++j) {
                float x = sacc[n][j];
                if (diag) {
                    const int tok = jb * 64 + n * 16 + l15;
                    const int qg  = qt * 64 + w * 16 + lhi * 4 + j;
                    if (tok > qg) x = -1e30f;
                }
                pv[n][j] = x;
            }
#pragma unroll
        for (int j = 0; j < 4; ++j) {
            float lmax = fmaxf(fmaxf(pv[0][j], pv[1][j]), fmaxf(pv[2][j], pv[3][j]));
            if (__any(lmax > m_run[j] + RESCALE_THR)) {
                float mt = lmax;
#pragma unroll
                for (int off = 1; off < 16; off <<= 1)
                    mt = fmaxf(mt, __shfl_xor(mt, off));
                const float mn = fmaxf(m_run[j], mt);
                const float alpha = __expf(m_run[j] - mn);
                m_run[j] = mn;
                l_part[j] *= alpha;
#pragma unroll
                for (int n2 = 0; n2 < 8; ++n2) acc[n2][j] *= alpha;
            }
            float ls = 0.f;
#pragma unroll
            for (int n = 0; n < 4; ++n) {
                float p = __expf(pv[n][j] - m_run[j]);
                pv[n][j] = p;
                ls += p;
            }
            l_part[j] += ls;
        }

        // ---- P -> per-wave LDS (A-fragment relayout)
        char* pb = sP[w];
#pragma unroll
        for (int n = 0; n < 4; ++n)
#pragma unroll
            for (int j = 0; j < 4; ++j) {
                const int r = lhi * 4 + j;
                const uint_t byte = (uint_t)(r * 128)
                    + (((uint_t)((n * 16 + l15) * 2)) ^ ((uint_t)((r & 7) << 4)));
                *(ushort_t*)(pb + byte) = f2bf(pv[n][j]);
            }

        // ---- O += P V
#pragma unroll
        for (int s2 = 0; s2 < 2; ++s2) {
            const uint_t pbyte = (uint_t)(l15 * 128)
                + (((uint_t)((s2 * 32 + lhi * 8) * 2)) ^ ((uint_t)((l15 & 7) << 4)));
            short8 pa = *(const short8*)(pb + pbyte);
#pragma unroll
            for (int n2 = 0; n2 < 8; ++n2) {
                const int dim = n2 * 16 + l15;
                const uint_t vbyte = (uint_t)(dim * 128)
                    + (((uint_t)((s2 * 32 + lhi * 8) * 2)) ^ ((uint_t)((dim & 7) << 4)));
                short8 vbf = *(const short8*)(vbuf + vbyte);
                acc[n2] = __builtin_amdgcn_mfma_f32_16x16x32_bf16(pa, vbf, acc[n2], 0, 0, 0);
            }
        }

        if (pf) __syncthreads();   // drains gll (vmcnt) + publishes next tile
    }

    // ---- epilogue: reduce per-lane l across 16-lane row group, store
#pragma unroll
    for (int j = 0; j < 4; ++j) {
        float lsum = l_part[j];
#pragma unroll
        for (int off = 1; off < 16; off <<= 1)
            lsum += __shfl_xor(lsum, off);
        const float inv = 1.0f / lsum;
        const int qg = qt * 64 + w * 16 + lhi * 4 + j;
        float* dst = out + (size_t)qg * Q_STRIDE + h * HEAD_DIM;
#pragma unroll
        for (int n2 = 0; n2 < 8; ++n2)
            dst[n2 * 16 + l15] = acc[n2][j] * inv;
    }
}

extern "C" void kernel_launch(void* const* d_in, const int* in_sizes, int n_in,
                              void* d_out, int out_size, void* d_ws, size_t ws_size,
                              hipStream_t stream) {
    const float* q   = (const float*)d_in[0];
    // d_in[1] (k) and d_in[2] (v) are dead under the reference's causal mask.
    const float* kvc = (const float*)d_in[3];
    const int*   bt  = (const int*)d_in[4];
    float* out = (float*)d_out;
    char*  wsb = (char*)d_ws;
    prep_kv<<<dim3(128), dim3(256), 0, stream>>>(kvc, bt, wsb);
    attn_main<<<dim3(512), dim3(256), 0, stream>>>(q, wsb, out);
}